// Round 1
// baseline (443.497 us; speedup 1.0000x reference)
//
#include <hip/hip_runtime.h>

#define B_SZ   32
#define LEN    2048
#define DIM    256
#define NST    64
#define OUTD   256
#define CHUNK  64
#define NCHUNK (LEN / CHUNK)     // 32
#define ROWS   (B_SZ * LEN)      // 65536

// ws layout (float offsets)
#define OFF_AT   0               // A_tilde [64][64]
#define OFF_A64  4096            // A_tilde^64 [64][64]
#define OFF_BT   8192            // B_tilde stored d-major: Bt[d][n], [256][64]
#define OFF_S    24576           // chunk-local final states [B][NCHUNK][64]
#define OFF_INST 90112           // chunk carry-in states    [B][NCHUNK][64]
#define OFF_U    155648          // u = x @ Bt  [ROWS][64]
#define OFF_H    4349952         // h states    [ROWS][64]
#define WS_FLOATS (OFF_H + ROWS * 64)   // 8,544,256 floats = 34.2 MB

// ---------------------------------------------------------------------------
// K1: build M = I + (dt/2)A, invert via Gauss-Jordan w/ partial pivoting,
//     A_tilde = Minv @ (I - (dt/2)A), Bt[d][n] = dt * (Minv @ B)[n][d]
// ---------------------------------------------------------------------------
__global__ __launch_bounds__(256) void k_prep(const float* __restrict__ A,
                                              const float* __restrict__ Bm,
                                              float* __restrict__ ws) {
  __shared__ __align__(16) float Mx[64 * 65];
  __shared__ __align__(16) float Iv[64 * 65];
  __shared__ float colk[64];
  __shared__ int pivs;
  const int t = threadIdx.x;

  for (int i = 0; i < 16; ++i) {
    int f = t + 256 * i;            // 0..4095
    int r = f >> 6, c = f & 63;
    float a = A[f];
    Mx[r * 65 + c] = 0.05f * a + (r == c ? 1.0f : 0.0f);
    Iv[r * 65 + c] = (r == c) ? 1.0f : 0.0f;
  }
  __syncthreads();

  for (int k = 0; k < 64; ++k) {
    if (t < 64) {                    // wave 0: argmax pivot
      float v = (t >= k) ? fabsf(Mx[t * 65 + k]) : -1.0f;
      int idx = t;
      for (int off = 32; off > 0; off >>= 1) {
        float ov = __shfl_xor(v, off);
        int oi = __shfl_xor(idx, off);
        if (ov > v) { v = ov; idx = oi; }
      }
      if (t == 0) pivs = idx;
    }
    __syncthreads();
    int p = pivs;
    if (p != k && t < 64) {
      float tmp = Mx[k * 65 + t]; Mx[k * 65 + t] = Mx[p * 65 + t]; Mx[p * 65 + t] = tmp;
      tmp = Iv[k * 65 + t]; Iv[k * 65 + t] = Iv[p * 65 + t]; Iv[p * 65 + t] = tmp;
    }
    __syncthreads();
    if (t < 64) colk[t] = Mx[t * 65 + k];
    __syncthreads();
    float rinv = 1.0f / colk[k];
    if (t < 64) {
      Mx[k * 65 + t] *= rinv;
      Iv[k * 65 + t] *= rinv;
    }
    __syncthreads();
    for (int i = 0; i < 16; ++i) {   // eliminate all rows != k
      int f = t + 256 * i;
      int r = f >> 6, c = f & 63;
      if (r != k) {
        float fct = colk[r];
        Mx[r * 65 + c] = fmaf(-fct, Mx[k * 65 + c], Mx[r * 65 + c]);
        Iv[r * 65 + c] = fmaf(-fct, Iv[k * 65 + c], Iv[r * 65 + c]);
      }
    }
    __syncthreads();
  }

  // NA = I - (dt/2) A into Mx
  for (int i = 0; i < 16; ++i) {
    int f = t + 256 * i;
    int r = f >> 6, c = f & 63;
    Mx[r * 65 + c] = (r == c ? 1.0f : 0.0f) - 0.05f * A[f];
  }
  __syncthreads();

  // At = Iv @ NA
  {
    int tr = t >> 4, tc = t & 15;
    int r0 = tr * 4, c0 = tc * 4;
    float acc[4][4] = {};
    for (int k = 0; k < 64; ++k) {
      float bv[4];
      for (int j = 0; j < 4; ++j) bv[j] = Mx[k * 65 + c0 + j];
      for (int i = 0; i < 4; ++i) {
        float av = Iv[(r0 + i) * 65 + k];
        for (int j = 0; j < 4; ++j) acc[i][j] = fmaf(av, bv[j], acc[i][j]);
      }
    }
    for (int i = 0; i < 4; ++i)
      for (int j = 0; j < 4; ++j)
        ws[OFF_AT + (r0 + i) * 64 + c0 + j] = acc[i][j];
  }
  __syncthreads();

  // Bt[d][n] = dt * sum_k Iv[n][k] * Bm[k][d]
  for (int db = 0; db < 4; ++db) {
    int d0 = db * 64;
    for (int i = 0; i < 16; ++i) {   // stage B block [k][dd] into Mx
      int f = t + 256 * i;
      int kk = f >> 6, dd = f & 63;
      Mx[kk * 65 + dd] = Bm[kk * 256 + d0 + dd];
    }
    __syncthreads();
    int n = t & 63, q = t >> 6;
    for (int jj = 0; jj < 16; ++jj) {
      int dd = q * 16 + jj;
      float acc = 0.0f;
      for (int k = 0; k < 64; ++k)
        acc = fmaf(Iv[n * 65 + k], Mx[k * 65 + dd], acc);
      ws[OFF_BT + (d0 + dd) * 64 + n] = 0.1f * acc;
    }
    __syncthreads();
  }
}

// ---------------------------------------------------------------------------
// K2: A64 = At^64 via 6 squarings, single workgroup
// ---------------------------------------------------------------------------
__global__ __launch_bounds__(256) void k_pow(float* __restrict__ ws) {
  __shared__ __align__(16) float Pa[64 * 68];
  __shared__ __align__(16) float Pb[64 * 68];
  const int t = threadIdx.x;
  for (int i = 0; i < 16; ++i) {
    int f = t + 256 * i; int r = f >> 6, c = f & 63;
    Pa[r * 68 + c] = ws[OFF_AT + f];
  }
  __syncthreads();
  float* src = Pa; float* dst = Pb;
  int tr = t >> 4, tc = t & 15;
  int r0 = tr * 4, c0 = tc * 4;
  for (int it = 0; it < 6; ++it) {
    float acc[4][4] = {};
    for (int k = 0; k < 64; ++k) {
      float bv[4];
      for (int j = 0; j < 4; ++j) bv[j] = src[k * 68 + c0 + j];
      for (int i = 0; i < 4; ++i) {
        float av = src[(r0 + i) * 68 + k];
        for (int j = 0; j < 4; ++j) acc[i][j] = fmaf(av, bv[j], acc[i][j]);
      }
    }
    for (int i = 0; i < 4; ++i)
      for (int j = 0; j < 4; ++j)
        dst[(r0 + i) * 68 + c0 + j] = acc[i][j];
    __syncthreads();
    float* tmp = src; src = dst; dst = tmp;
  }
  for (int i = 0; i < 16; ++i) {
    int f = t + 256 * i; int r = f >> 6, c = f & 63;
    ws[OFF_A64 + f] = src[r * 68 + c];
  }
}

// ---------------------------------------------------------------------------
// K3: u[row][n] = sum_d x[row][d] * Bt[d][n]   (64-row x 64-col tile per wg)
// ---------------------------------------------------------------------------
__global__ __launch_bounds__(256) void k_ugemm(const float* __restrict__ x,
                                               float* __restrict__ ws) {
  __shared__ __align__(16) float xs[64 * 68];
  __shared__ __align__(16) float bs[64 * 68];
  const float* Bt = ws + OFF_BT;
  float* u = ws + OFF_U;
  const int t = threadIdx.x;
  const int rowbase = blockIdx.x * 64;
  const int tr = t >> 4, tc = t & 15;
  const int r0 = tr * 4, n0 = tc * 4;
  float acc[4][4] = {};
  for (int db = 0; db < 4; ++db) {
    int d0 = db * 64;
    for (int i = 0; i < 4; ++i) {
      int e = 4 * (t + 256 * i);           // 0..4092
      int rr = e >> 6, dd = e & 63;
      *(float4*)(xs + rr * 68 + dd) =
          *(const float4*)(x + (size_t)(rowbase + rr) * 256 + d0 + dd);
      *(float4*)(bs + rr * 68 + dd) = *(const float4*)(Bt + d0 * 64 + e);
    }
    __syncthreads();
    for (int k = 0; k < 64; ++k) {
      float4 bv4 = *(const float4*)(bs + k * 68 + n0);
      float bv[4] = {bv4.x, bv4.y, bv4.z, bv4.w};
      for (int i = 0; i < 4; ++i) {
        float av = xs[(r0 + i) * 68 + k];
        for (int j = 0; j < 4; ++j) acc[i][j] = fmaf(av, bv[j], acc[i][j]);
      }
    }
    __syncthreads();
  }
  for (int i = 0; i < 4; ++i)
    *(float4*)(u + (size_t)(rowbase + r0 + i) * 64 + n0) =
        make_float4(acc[i][0], acc[i][1], acc[i][2], acc[i][3]);
}

// ---------------------------------------------------------------------------
// Scan helpers: 64x64 matvec step. areg[j] = M[r][16q+j]; h in LDS.
// ---------------------------------------------------------------------------
__device__ __forceinline__ void load_areg(const float* __restrict__ M, int r,
                                          int q, float areg[16]) {
  const float4* ap = (const float4*)(M + r * 64 + q * 16);
  float4 a0 = ap[0], a1 = ap[1], a2 = ap[2], a3 = ap[3];
  areg[0] = a0.x; areg[1] = a0.y; areg[2] = a0.z; areg[3] = a0.w;
  areg[4] = a1.x; areg[5] = a1.y; areg[6] = a1.z; areg[7] = a1.w;
  areg[8] = a2.x; areg[9] = a2.y; areg[10] = a2.z; areg[11] = a2.w;
  areg[12] = a3.x; areg[13] = a3.y; areg[14] = a3.z; areg[15] = a3.w;
}

// computes partial products, barrier, returns reduced matvec row (valid t<64)
__device__ __forceinline__ float matvec_step(const float areg[16],
                                             const float* __restrict__ hcur,
                                             float* __restrict__ part, int r,
                                             int q, int t) {
  float4 ha = *(const float4*)(hcur + q * 16);
  float4 hb = *(const float4*)(hcur + q * 16 + 4);
  float4 hc = *(const float4*)(hcur + q * 16 + 8);
  float4 hd = *(const float4*)(hcur + q * 16 + 12);
  float p0 = fmaf(areg[0], ha.x, fmaf(areg[4], hb.x, fmaf(areg[8], hc.x, areg[12] * hd.x)));
  float p1 = fmaf(areg[1], ha.y, fmaf(areg[5], hb.y, fmaf(areg[9], hc.y, areg[13] * hd.y)));
  float p2 = fmaf(areg[2], ha.z, fmaf(areg[6], hb.z, fmaf(areg[10], hc.z, areg[14] * hd.z)));
  float p3 = fmaf(areg[3], ha.w, fmaf(areg[7], hb.w, fmaf(areg[11], hc.w, areg[15] * hd.w)));
  part[q * 68 + r] = (p0 + p1) + (p2 + p3);
  __syncthreads();
  float s = 0.0f;
  if (t < 64) s = part[t] + part[68 + t] + part[136 + t] + part[204 + t];
  return s;
}

// ---------------------------------------------------------------------------
// K4/K6: chunk-local scan. phase=1: h0=0, emit final state to S.
//        phase=3: h0=INST[b][c], emit every h to H.
// ---------------------------------------------------------------------------
__global__ __launch_bounds__(256) void k_chunk(float* __restrict__ ws, int phase) {
  __shared__ __align__(16) float hcur[64];
  __shared__ __align__(16) float part[4 * 68];
  __shared__ __align__(16) float ulds[CHUNK * 64];
  const int t = threadIdx.x;
  const int c = blockIdx.x, b = blockIdx.y;
  const int r = t & 63, q = t >> 6;
  float areg[16];
  load_areg(ws + OFF_AT, r, q, areg);
  const float* u = ws + OFF_U + (size_t)(b * LEN + c * CHUNK) * 64;
  for (int i = 0; i < 4; ++i) {
    int e = 4 * (t + 256 * i);
    *(float4*)(ulds + e) = *(const float4*)(u + e);
  }
  if (t < 64)
    hcur[t] = (phase == 3) ? ws[OFF_INST + (b * NCHUNK + c) * 64 + t] : 0.0f;
  __syncthreads();
  for (int st = 0; st < CHUNK; ++st) {
    float s = matvec_step(areg, hcur, part, r, q, t);
    if (t < 64) {
      float hn = s + ulds[st * 64 + t];
      hcur[t] = hn;
      if (phase == 3)
        ws[OFF_H + (size_t)(b * LEN + c * CHUNK + st) * 64 + t] = hn;
      else if (st == CHUNK - 1)
        ws[OFF_S + (b * NCHUNK + c) * 64 + t] = hn;
    }
    __syncthreads();
  }
}

// ---------------------------------------------------------------------------
// K5: sequential carry combine per batch: INST[b][0]=0,
//     INST[b][c] = A64 @ INST[b][c-1] + S[b][c-1]
// ---------------------------------------------------------------------------
__global__ __launch_bounds__(256) void k_carry(float* __restrict__ ws) {
  __shared__ __align__(16) float hcur[64];
  __shared__ __align__(16) float part[4 * 68];
  __shared__ __align__(16) float slds[NCHUNK * 64];
  const int t = threadIdx.x;
  const int b = blockIdx.x;
  const int r = t & 63, q = t >> 6;
  float areg[16];
  load_areg(ws + OFF_A64, r, q, areg);
  for (int i = 0; i < 2; ++i) {
    int e = 4 * (t + 256 * i);                 // 0..2044
    *(float4*)(slds + e) = *(const float4*)(ws + OFF_S + b * NCHUNK * 64 + e);
  }
  if (t < 64) {
    hcur[t] = 0.0f;
    ws[OFF_INST + (b * NCHUNK) * 64 + t] = 0.0f;
  }
  __syncthreads();
  for (int c = 1; c < NCHUNK; ++c) {
    float s = matvec_step(areg, hcur, part, r, q, t);
    if (t < 64) {
      float hn = s + slds[(c - 1) * 64 + t];
      hcur[t] = hn;
      ws[OFF_INST + (b * NCHUNK + c) * 64 + t] = hn;
    }
    __syncthreads();
  }
}

// ---------------------------------------------------------------------------
// K7: y[row][o] = sum_n h[row][n] * C[o][n]  (64-row x 64-o tile per wg)
// ---------------------------------------------------------------------------
__global__ __launch_bounds__(256) void k_ygemm(const float* __restrict__ Cm,
                                               const float* __restrict__ ws,
                                               float* __restrict__ y) {
  __shared__ __align__(16) float hs[64 * 68];
  __shared__ __align__(16) float cs[64 * 68];
  const int t = threadIdx.x;
  const int rowbase = blockIdx.x * 64;
  const int o0 = blockIdx.y * 64;
  const float* h = ws + OFF_H;
  for (int i = 0; i < 4; ++i) {
    int e = 4 * (t + 256 * i);
    int rr = e >> 6, nn = e & 63;
    *(float4*)(hs + rr * 68 + nn) =
        *(const float4*)(h + (size_t)rowbase * 64 + e);
    float4 cv = *(const float4*)(Cm + (size_t)(o0 + rr) * 64 + nn);
    cs[(nn + 0) * 68 + rr] = cv.x;     // transposed: cs[n][o']
    cs[(nn + 1) * 68 + rr] = cv.y;
    cs[(nn + 2) * 68 + rr] = cv.z;
    cs[(nn + 3) * 68 + rr] = cv.w;
  }
  __syncthreads();
  const int tr = t >> 4, tc = t & 15;
  const int r0 = tr * 4, c0 = tc * 4;
  float acc[4][4] = {};
  for (int k = 0; k < 64; ++k) {
    float4 cv4 = *(const float4*)(cs + k * 68 + c0);
    float cv[4] = {cv4.x, cv4.y, cv4.z, cv4.w};
    for (int i = 0; i < 4; ++i) {
      float hv = hs[(r0 + i) * 68 + k];
      for (int j = 0; j < 4; ++j) acc[i][j] = fmaf(hv, cv[j], acc[i][j]);
    }
  }
  for (int i = 0; i < 4; ++i)
    *(float4*)(y + (size_t)(rowbase + r0 + i) * 256 + o0 + c0) =
        make_float4(acc[i][0], acc[i][1], acc[i][2], acc[i][3]);
}

// ---------------------------------------------------------------------------
extern "C" void kernel_launch(void* const* d_in, const int* in_sizes, int n_in,
                              void* d_out, int out_size, void* d_ws,
                              size_t ws_size, hipStream_t stream) {
  const float* x = (const float*)d_in[0];
  const float* A = (const float*)d_in[1];
  const float* Bm = (const float*)d_in[2];
  const float* Cm = (const float*)d_in[3];
  float* y = (float*)d_out;
  float* ws = (float*)d_ws;
  if (ws_size < (size_t)WS_FLOATS * sizeof(float)) return;  // scratch too small

  hipLaunchKernelGGL(k_prep, dim3(1), dim3(256), 0, stream, A, Bm, ws);
  hipLaunchKernelGGL(k_pow, dim3(1), dim3(256), 0, stream, ws);
  hipLaunchKernelGGL(k_ugemm, dim3(ROWS / 64), dim3(256), 0, stream, x, ws);
  hipLaunchKernelGGL(k_chunk, dim3(NCHUNK, B_SZ), dim3(256), 0, stream, ws, 1);
  hipLaunchKernelGGL(k_carry, dim3(B_SZ), dim3(256), 0, stream, ws);
  hipLaunchKernelGGL(k_chunk, dim3(NCHUNK, B_SZ), dim3(256), 0, stream, ws, 3);
  hipLaunchKernelGGL(k_ygemm, dim3(ROWS / 64, OUTD / 64), dim3(256), 0, stream,
                     Cm, ws, y);
}

// Round 2
// 294.129 us; speedup vs baseline: 1.5078x; 1.5078x over previous
//
#include <hip/hip_runtime.h>

#define B_SZ   32
#define LEN    2048
#define DIM    256
#define NST    64
#define OUTD   256
#define CHUNK  64
#define NCHUNK (LEN / CHUNK)     // 32
#define ROWS   (B_SZ * LEN)      // 65536

// ws layout (float offsets)
#define OFF_AT   0               // A_tilde [64][64]
#define OFF_A64  4096            // A_tilde^64 [64][64]
#define OFF_BT   8192            // B_tilde stored d-major: Bt[d][n], [256][64]
#define OFF_S    24576           // chunk-local final states [B][NCHUNK][64]
#define OFF_INST 90112           // chunk carry-in states    [B][NCHUNK][64]
#define OFF_U    155648          // u = x @ Bt  [ROWS][64]
#define OFF_H    4349952         // h states    [ROWS][64]
#define WS_FLOATS (OFF_H + ROWS * 64)   // 8,544,256 floats = 34.2 MB

// ---------------------------------------------------------------------------
// K1 (merged prep+pow): register-resident Gauss-Jordan (no pivoting) on
// M = I + (dt/2)A with 1024 threads; At = 2*Minv - I (algebraic identity,
// no matmul); Bt = dt * Minv @ B via broadcast/b128 LDS matmul; A64 = At^64
// via 6 squarings with broadcast-A / stride-1-B LDS access.
// Thread layout for GJ: t = tr*64+tc; thread owns M[4tr+i][tc], Inv[4tr+i][tc].
// ---------------------------------------------------------------------------
__global__ __launch_bounds__(1024) void k_prep(const float* __restrict__ A,
                                               const float* __restrict__ Bm,
                                               float* __restrict__ ws) {
  __shared__ __align__(16) float sh[16384];   // 64 KB, manually carved
  float* Ilds  = sh;                          // [64][65]  (Minv, row-major pad 65)
  float* rowkM = sh + 4160;                   // [64]
  float* rowkI = sh + 4224;                   // [64]
  float* colk  = sh + 4288;                   // [64]
  float* bs    = sh + 4352;                   // [64][132] B staging (Bt phase)
  float* Pa    = sh + 4352;                   // [64][68]  (aliases bs; pow phase)
  float* Pb    = sh + 8704;                   // [64][68]

  const int t  = threadIdx.x;
  const int tc = t & 63;
  const int tr = t >> 6;                      // 0..15

  float Mreg[4], Ireg[4];
  for (int i = 0; i < 4; ++i) {
    int r = 4 * tr + i;
    Mreg[i] = 0.05f * A[r * 64 + tc] + (r == tc ? 1.0f : 0.0f);
    Ireg[i] = (r == tc) ? 1.0f : 0.0f;
  }

  // ---- Gauss-Jordan without pivoting: M -> I, Ireg -> Minv ----
  for (int k = 0; k < 64; ++k) {
    if (tr == (k >> 2)) { rowkM[tc] = Mreg[k & 3]; rowkI[tc] = Ireg[k & 3]; }
    if (tc == k) {
      colk[4 * tr + 0] = Mreg[0]; colk[4 * tr + 1] = Mreg[1];
      colk[4 * tr + 2] = Mreg[2]; colk[4 * tr + 3] = Mreg[3];
    }
    __syncthreads();
    float rinv = 1.0f / rowkM[k];
    float rM = rowkM[tc] * rinv;              // scaled pivot row, this column
    float rI = rowkI[tc] * rinv;
    for (int i = 0; i < 4; ++i) {
      int r = 4 * tr + i;
      float f = colk[r];
      if (r == k) { Mreg[i] = rM; Ireg[i] = rI; }
      else {
        Mreg[i] = fmaf(-f, rM, Mreg[i]);
        Ireg[i] = fmaf(-f, rI, Ireg[i]);
      }
    }
    __syncthreads();
  }

  // ---- dump Minv to LDS; At = 2*Minv - I straight to global ----
  for (int i = 0; i < 4; ++i) {
    int r = 4 * tr + i;
    Ilds[r * 65 + tc] = Ireg[i];
    ws[OFF_AT + r * 64 + tc] = 2.0f * Ireg[i] - (r == tc ? 1.0f : 0.0f);
  }
  __syncthreads();

  // ---- Bt[d][n] = 0.1 * sum_k Minv[n][k] * B[k][d], two 128-col rounds ----
  // wave = fixed tr(g), lanes vary n -> av stride-1 (2-way free), bv broadcast
  const int n = tc, g = tr;
  for (int rd = 0; rd < 2; ++rd) {
    for (int i = 0; i < 2; ++i) {
      int e = 4 * (t + 1024 * i);             // 0..8188
      int kk = e >> 7, cc = e & 127;
      *(float4*)(bs + kk * 132 + cc) =
          *(const float4*)(Bm + kk * 256 + rd * 128 + cc);
    }
    __syncthreads();
    float acc[2][4] = {};
    for (int k = 0; k < 64; ++k) {
      float av = Ilds[n * 65 + k];
      for (int db = 0; db < 2; ++db) {
        float4 bv = *(const float4*)(bs + k * 132 + db * 64 + 4 * g);
        acc[db][0] = fmaf(av, bv.x, acc[db][0]);
        acc[db][1] = fmaf(av, bv.y, acc[db][1]);
        acc[db][2] = fmaf(av, bv.z, acc[db][2]);
        acc[db][3] = fmaf(av, bv.w, acc[db][3]);
      }
    }
    for (int db = 0; db < 2; ++db)
      for (int j = 0; j < 4; ++j) {
        int d = rd * 128 + db * 64 + 4 * g + j;
        ws[OFF_BT + d * 64 + n] = 0.1f * acc[db][j];
      }
    __syncthreads();
  }

  // ---- Pa = At (still in registers), then 6 squarings -> A64 ----
  for (int i = 0; i < 4; ++i) {
    int r = 4 * tr + i;
    Pa[r * 68 + tc] = 2.0f * Ireg[i] - (r == tc ? 1.0f : 0.0f);
  }
  __syncthreads();
  float* src = Pa; float* dst = Pb;
  const int c = tc; const int r0 = 4 * tr;
  for (int it = 0; it < 6; ++it) {
    float acc[4] = {};
    for (int k = 0; k < 64; ++k) {
      float bv = src[k * 68 + c];             // lane-varying stride-1
      acc[0] = fmaf(src[(r0 + 0) * 68 + k], bv, acc[0]);   // broadcasts
      acc[1] = fmaf(src[(r0 + 1) * 68 + k], bv, acc[1]);
      acc[2] = fmaf(src[(r0 + 2) * 68 + k], bv, acc[2]);
      acc[3] = fmaf(src[(r0 + 3) * 68 + k], bv, acc[3]);
    }
    for (int i = 0; i < 4; ++i) dst[(r0 + i) * 68 + c] = acc[i];
    __syncthreads();
    float* tmp = src; src = dst; dst = tmp;
  }
  {
    int f = 4 * t;                            // 0..4092
    int r = f >> 6, cc = f & 63;
    float4 v = *(const float4*)(src + r * 68 + cc);
    *(float4*)(ws + OFF_A64 + f) = v;
  }
}

// ---------------------------------------------------------------------------
// K3: u[row][n] = sum_d x[row][d] * Bt[d][n]   (64-row x 64-col tile per wg)
// ---------------------------------------------------------------------------
__global__ __launch_bounds__(256) void k_ugemm(const float* __restrict__ x,
                                               float* __restrict__ ws) {
  __shared__ __align__(16) float xs[64 * 68];
  __shared__ __align__(16) float bs[64 * 68];
  const float* Bt = ws + OFF_BT;
  float* u = ws + OFF_U;
  const int t = threadIdx.x;
  const int rowbase = blockIdx.x * 64;
  const int tr = t >> 4, tc = t & 15;
  const int r0 = tr * 4, n0 = tc * 4;
  float acc[4][4] = {};
  for (int db = 0; db < 4; ++db) {
    int d0 = db * 64;
    for (int i = 0; i < 4; ++i) {
      int e = 4 * (t + 256 * i);           // 0..4092
      int rr = e >> 6, dd = e & 63;
      *(float4*)(xs + rr * 68 + dd) =
          *(const float4*)(x + (size_t)(rowbase + rr) * 256 + d0 + dd);
      *(float4*)(bs + rr * 68 + dd) = *(const float4*)(Bt + d0 * 64 + e);
    }
    __syncthreads();
    for (int k = 0; k < 64; ++k) {
      float4 bv4 = *(const float4*)(bs + k * 68 + n0);
      float bv[4] = {bv4.x, bv4.y, bv4.z, bv4.w};
      for (int i = 0; i < 4; ++i) {
        float av = xs[(r0 + i) * 68 + k];
        for (int j = 0; j < 4; ++j) acc[i][j] = fmaf(av, bv[j], acc[i][j]);
      }
    }
    __syncthreads();
  }
  for (int i = 0; i < 4; ++i)
    *(float4*)(u + (size_t)(rowbase + r0 + i) * 64 + n0) =
        make_float4(acc[i][0], acc[i][1], acc[i][2], acc[i][3]);
}

// ---------------------------------------------------------------------------
// Scan helpers: 64x64 matvec step. areg[j] = M[r][16q+j]; h in LDS.
// ---------------------------------------------------------------------------
__device__ __forceinline__ void load_areg(const float* __restrict__ M, int r,
                                          int q, float areg[16]) {
  const float4* ap = (const float4*)(M + r * 64 + q * 16);
  float4 a0 = ap[0], a1 = ap[1], a2 = ap[2], a3 = ap[3];
  areg[0] = a0.x; areg[1] = a0.y; areg[2] = a0.z; areg[3] = a0.w;
  areg[4] = a1.x; areg[5] = a1.y; areg[6] = a1.z; areg[7] = a1.w;
  areg[8] = a2.x; areg[9] = a2.y; areg[10] = a2.z; areg[11] = a2.w;
  areg[12] = a3.x; areg[13] = a3.y; areg[14] = a3.z; areg[15] = a3.w;
}

// computes partial products, barrier, returns reduced matvec row (valid t<64)
__device__ __forceinline__ float matvec_step(const float areg[16],
                                             const float* __restrict__ hcur,
                                             float* __restrict__ part, int r,
                                             int q, int t) {
  float4 ha = *(const float4*)(hcur + q * 16);
  float4 hb = *(const float4*)(hcur + q * 16 + 4);
  float4 hc = *(const float4*)(hcur + q * 16 + 8);
  float4 hd = *(const float4*)(hcur + q * 16 + 12);
  float p0 = fmaf(areg[0], ha.x, fmaf(areg[4], hb.x, fmaf(areg[8], hc.x, areg[12] * hd.x)));
  float p1 = fmaf(areg[1], ha.y, fmaf(areg[5], hb.y, fmaf(areg[9], hc.y, areg[13] * hd.y)));
  float p2 = fmaf(areg[2], ha.z, fmaf(areg[6], hb.z, fmaf(areg[10], hc.z, areg[14] * hd.z)));
  float p3 = fmaf(areg[3], ha.w, fmaf(areg[7], hb.w, fmaf(areg[11], hc.w, areg[15] * hd.w)));
  part[q * 68 + r] = (p0 + p1) + (p2 + p3);
  __syncthreads();
  float s = 0.0f;
  if (t < 64) s = part[t] + part[68 + t] + part[136 + t] + part[204 + t];
  return s;
}

// ---------------------------------------------------------------------------
// K4/K6: chunk-local scan. phase=1: h0=0, emit final state to S.
//        phase=3: h0=INST[b][c], emit every h to H.
// ---------------------------------------------------------------------------
__global__ __launch_bounds__(256) void k_chunk(float* __restrict__ ws, int phase) {
  __shared__ __align__(16) float hcur[64];
  __shared__ __align__(16) float part[4 * 68];
  __shared__ __align__(16) float ulds[CHUNK * 64];
  const int t = threadIdx.x;
  const int c = blockIdx.x, b = blockIdx.y;
  const int r = t & 63, q = t >> 6;
  float areg[16];
  load_areg(ws + OFF_AT, r, q, areg);
  const float* u = ws + OFF_U + (size_t)(b * LEN + c * CHUNK) * 64;
  for (int i = 0; i < 4; ++i) {
    int e = 4 * (t + 256 * i);
    *(float4*)(ulds + e) = *(const float4*)(u + e);
  }
  if (t < 64)
    hcur[t] = (phase == 3) ? ws[OFF_INST + (b * NCHUNK + c) * 64 + t] : 0.0f;
  __syncthreads();
  for (int st = 0; st < CHUNK; ++st) {
    float s = matvec_step(areg, hcur, part, r, q, t);
    if (t < 64) {
      float hn = s + ulds[st * 64 + t];
      hcur[t] = hn;
      if (phase == 3)
        ws[OFF_H + (size_t)(b * LEN + c * CHUNK + st) * 64 + t] = hn;
      else if (st == CHUNK - 1)
        ws[OFF_S + (b * NCHUNK + c) * 64 + t] = hn;
    }
    __syncthreads();
  }
}

// ---------------------------------------------------------------------------
// K5: sequential carry combine per batch: INST[b][0]=0,
//     INST[b][c] = A64 @ INST[b][c-1] + S[b][c-1]
// ---------------------------------------------------------------------------
__global__ __launch_bounds__(256) void k_carry(float* __restrict__ ws) {
  __shared__ __align__(16) float hcur[64];
  __shared__ __align__(16) float part[4 * 68];
  __shared__ __align__(16) float slds[NCHUNK * 64];
  const int t = threadIdx.x;
  const int b = blockIdx.x;
  const int r = t & 63, q = t >> 6;
  float areg[16];
  load_areg(ws + OFF_A64, r, q, areg);
  for (int i = 0; i < 2; ++i) {
    int e = 4 * (t + 256 * i);                 // 0..2044
    *(float4*)(slds + e) = *(const float4*)(ws + OFF_S + b * NCHUNK * 64 + e);
  }
  if (t < 64) {
    hcur[t] = 0.0f;
    ws[OFF_INST + (b * NCHUNK) * 64 + t] = 0.0f;
  }
  __syncthreads();
  for (int c = 1; c < NCHUNK; ++c) {
    float s = matvec_step(areg, hcur, part, r, q, t);
    if (t < 64) {
      float hn = s + slds[(c - 1) * 64 + t];
      hcur[t] = hn;
      ws[OFF_INST + (b * NCHUNK + c) * 64 + t] = hn;
    }
    __syncthreads();
  }
}

// ---------------------------------------------------------------------------
// K7: y[row][o] = sum_n h[row][n] * C[o][n]  (64-row x 64-o tile per wg)
// ---------------------------------------------------------------------------
__global__ __launch_bounds__(256) void k_ygemm(const float* __restrict__ Cm,
                                               const float* __restrict__ ws,
                                               float* __restrict__ y) {
  __shared__ __align__(16) float hs[64 * 68];
  __shared__ __align__(16) float cs[64 * 68];
  const int t = threadIdx.x;
  const int rowbase = blockIdx.x * 64;
  const int o0 = blockIdx.y * 64;
  const float* h = ws + OFF_H;
  for (int i = 0; i < 4; ++i) {
    int e = 4 * (t + 256 * i);
    int rr = e >> 6, nn = e & 63;
    *(float4*)(hs + rr * 68 + nn) =
        *(const float4*)(h + (size_t)rowbase * 64 + e);
    float4 cv = *(const float4*)(Cm + (size_t)(o0 + rr) * 64 + nn);
    cs[(nn + 0) * 68 + rr] = cv.x;     // transposed: cs[n][o']
    cs[(nn + 1) * 68 + rr] = cv.y;
    cs[(nn + 2) * 68 + rr] = cv.z;
    cs[(nn + 3) * 68 + rr] = cv.w;
  }
  __syncthreads();
  const int tr = t >> 4, tc = t & 15;
  const int r0 = tr * 4, c0 = tc * 4;
  float acc[4][4] = {};
  for (int k = 0; k < 64; ++k) {
    float4 cv4 = *(const float4*)(cs + k * 68 + c0);
    float cv[4] = {cv4.x, cv4.y, cv4.z, cv4.w};
    for (int i = 0; i < 4; ++i) {
      float hv = hs[(r0 + i) * 68 + k];
      for (int j = 0; j < 4; ++j) acc[i][j] = fmaf(hv, cv[j], acc[i][j]);
    }
  }
  for (int i = 0; i < 4; ++i)
    *(float4*)(y + (size_t)(rowbase + r0 + i) * 256 + o0 + c0) =
        make_float4(acc[i][0], acc[i][1], acc[i][2], acc[i][3]);
}

// ---------------------------------------------------------------------------
extern "C" void kernel_launch(void* const* d_in, const int* in_sizes, int n_in,
                              void* d_out, int out_size, void* d_ws,
                              size_t ws_size, hipStream_t stream) {
  const float* x = (const float*)d_in[0];
  const float* A = (const float*)d_in[1];
  const float* Bm = (const float*)d_in[2];
  const float* Cm = (const float*)d_in[3];
  float* y = (float*)d_out;
  float* ws = (float*)d_ws;
  if (ws_size < (size_t)WS_FLOATS * sizeof(float)) return;  // scratch too small

  hipLaunchKernelGGL(k_prep, dim3(1), dim3(1024), 0, stream, A, Bm, ws);
  hipLaunchKernelGGL(k_ugemm, dim3(ROWS / 64), dim3(256), 0, stream, x, ws);
  hipLaunchKernelGGL(k_chunk, dim3(NCHUNK, B_SZ), dim3(256), 0, stream, ws, 1);
  hipLaunchKernelGGL(k_carry, dim3(B_SZ), dim3(256), 0, stream, ws);
  hipLaunchKernelGGL(k_chunk, dim3(NCHUNK, B_SZ), dim3(256), 0, stream, ws, 3);
  hipLaunchKernelGGL(k_ygemm, dim3(ROWS / 64, OUTD / 64), dim3(256), 0, stream,
                     Cm, ws, y);
}

// Round 3
// 259.600 us; speedup vs baseline: 1.7084x; 1.1330x over previous
//
#include <hip/hip_runtime.h>

#define B_SZ   32
#define LEN    2048
#define DIM    256
#define NST    64
#define OUTD   256
#define CHUNK  64
#define NCHUNK (LEN / CHUNK)     // 32
#define ROWS   (B_SZ * LEN)      // 65536

// ws layout (float offsets)
#define OFF_AT   0               // A_tilde [64][64]
#define OFF_A64  4096            // A_tilde^64 [64][64]
#define OFF_MT   8192            // MinvT[m][n] = Minv[n][m], [64][64]
#define OFF_S    12288           // chunk-local final states [B][NCHUNK][64]
#define OFF_INST 77824           // chunk carry-in states    [B][NCHUNK][64]
#define OFF_U    143360          // u = dt * v @ MinvT  [ROWS][64]
#define OFF_H    4337664         // h states [ROWS][64]; v aliases H (v dead by chunk3)
#define OFF_V    OFF_H
#define WS_FLOATS (OFF_H + ROWS * 64)   // 8,531,968 floats = 32.5 MiB

// ---------------------------------------------------------------------------
// K_A fused: block 0 = prep core (GJ inverse of M = I + (dt/2)A with 1 barrier
// per iteration; At = 2*Minv - I; MinvT; A64 = At^64 via 6 squarings).
// Blocks 1..1024 = v[row][m] = sum_d x[row][d] * B[m][d]  (prep-independent).
// ---------------------------------------------------------------------------
__global__ __launch_bounds__(256) void k_fused0(const float* __restrict__ A,
                                                const float* __restrict__ Bm,
                                                const float* __restrict__ x,
                                                float* __restrict__ ws) {
  __shared__ __align__(16) float sh[9088];    // 36.4 KB
  const int t = threadIdx.x;

  if (blockIdx.x == 0) {
    // ---- carve: Pa [64][68] (also Ilds [64][65]), Pb [64][68], GJ bufs ----
    float* Pa  = sh;            // 4352
    float* Pb  = sh + 4352;     // 4352
    float* rbM = sh + 8704;     // [2][64]
    float* rbI = sh + 8832;     // [2][64]
    float* cb  = sh + 8960;     // [2][64]

    const int tc = t & 63;      // column owned
    const int tr = t >> 6;      // 0..3; rows 16*tr+i
    float M[16], Iv[16];
    for (int i = 0; i < 16; ++i) {
      int r = 16 * tr + i;
      M[i] = 0.05f * A[r * 64 + tc] + (r == tc ? 1.0f : 0.0f);
      Iv[i] = (r == tc) ? 1.0f : 0.0f;
    }
    // publish row 0 / col 0
    if (tr == 0) { rbM[tc] = M[0]; rbI[tc] = Iv[0]; }
    if (tc == 0)
      for (int i = 0; i < 16; ++i) cb[16 * tr + i] = M[i];
    __syncthreads();

    // ---- Gauss-Jordan, no pivoting, 1 barrier/iter ----
#pragma unroll
    for (int k = 0; k < 64; ++k) {
      const int cur = (k & 1) * 64, nxt = ((k + 1) & 1) * 64;
      float rinv = 1.0f / rbM[cur + k];
      float rM = rbM[cur + tc] * rinv;
      float rI = rbI[cur + tc] * rinv;
#pragma unroll
      for (int i = 0; i < 16; ++i) {
        int r = 16 * tr + i;
        if (r == k) { M[i] = rM; Iv[i] = rI; }
        else {
          float f = cb[cur + r];
          M[i] = fmaf(-f, rM, M[i]);
          Iv[i] = fmaf(-f, rI, Iv[i]);
        }
      }
      if (k < 63) {
        if (tr == ((k + 1) >> 4)) {
          rbM[nxt + tc] = M[(k + 1) & 15];
          rbI[nxt + tc] = Iv[(k + 1) & 15];
        }
        if (tc == k + 1)
          for (int i = 0; i < 16; ++i) cb[nxt + 16 * tr + i] = M[i];
      }
      __syncthreads();
    }

    // ---- At = 2*Minv - I to global; Minv to LDS for transpose ----
    for (int i = 0; i < 16; ++i) {
      int r = 16 * tr + i;
      ws[OFF_AT + r * 64 + tc] = 2.0f * Iv[i] - (r == tc ? 1.0f : 0.0f);
      Pa[r * 65 + tc] = Iv[i];               // Ilds (pad 65)
    }
    __syncthreads();
    // MT[m][n] = Minv[n][m]; coalesced global writes, stride-65 LDS reads
    for (int i = 0; i < 16; ++i) {
      int m = 16 * tr + i;
      ws[OFF_MT + m * 64 + tc] = Pa[tc * 65 + m];
    }
    __syncthreads();

    // ---- Pa = At [64][68]; 6 squarings -> A64 ----
    for (int i = 0; i < 16; ++i) {
      int r = 16 * tr + i;
      Pa[r * 68 + tc] = 2.0f * Iv[i] - (r == tc ? 1.0f : 0.0f);
    }
    __syncthreads();
    float* src = Pa; float* dst = Pb;
    const int r0 = 4 * (t >> 4), c0 = 4 * (t & 15);
    for (int it = 0; it < 6; ++it) {
      float acc[4][4] = {};
      for (int k = 0; k < 64; ++k) {
        float4 bv = *(const float4*)(src + k * 68 + c0);
        for (int i = 0; i < 4; ++i) {
          float av = src[(r0 + i) * 68 + k];
          acc[i][0] = fmaf(av, bv.x, acc[i][0]);
          acc[i][1] = fmaf(av, bv.y, acc[i][1]);
          acc[i][2] = fmaf(av, bv.z, acc[i][2]);
          acc[i][3] = fmaf(av, bv.w, acc[i][3]);
        }
      }
      for (int i = 0; i < 4; ++i)
        *(float4*)(dst + (r0 + i) * 68 + c0) =
            make_float4(acc[i][0], acc[i][1], acc[i][2], acc[i][3]);
      __syncthreads();
      float* tmp = src; src = dst; dst = tmp;
    }
    for (int i = 0; i < 4; ++i) {
      int f = 4 * (t + 256 * i);
      int r = f >> 6, c = f & 63;
      *(float4*)(ws + OFF_A64 + f) = *(const float4*)(src + r * 68 + c);
    }
  } else {
    // ---- v-GEMM: v[row][m] = sum_d x[row][d]*B[m][d], 64-row tile ----
    float* xsT = sh;            // [64][68]: xsT[dd][rr]
    float* bsT = sh + 4352;     // [64][68]: bsT[dd][m]
    const int rowbase = (blockIdx.x - 1) * 64;
    const int r0 = 4 * (t >> 4), m0 = 4 * (t & 15);
    float acc[4][4] = {};
    for (int db = 0; db < 4; ++db) {
      int d0 = db * 64;
      for (int i = 0; i < 4; ++i) {
        int e = 4 * (t + 256 * i);           // 0..4092
        int rr = e >> 6, dd = e & 63;        // rr: row / m index
        float4 xv = *(const float4*)(x + (size_t)(rowbase + rr) * 256 + d0 + dd);
        xsT[(dd + 0) * 68 + rr] = xv.x;
        xsT[(dd + 1) * 68 + rr] = xv.y;
        xsT[(dd + 2) * 68 + rr] = xv.z;
        xsT[(dd + 3) * 68 + rr] = xv.w;
        float4 bv = *(const float4*)(Bm + (size_t)rr * 256 + d0 + dd);
        bsT[(dd + 0) * 68 + rr] = bv.x;
        bsT[(dd + 1) * 68 + rr] = bv.y;
        bsT[(dd + 2) * 68 + rr] = bv.z;
        bsT[(dd + 3) * 68 + rr] = bv.w;
      }
      __syncthreads();
      for (int k = 0; k < 64; ++k) {
        float4 av4 = *(const float4*)(xsT + k * 68 + r0);
        float4 bv4 = *(const float4*)(bsT + k * 68 + m0);
        float av[4] = {av4.x, av4.y, av4.z, av4.w};
        float bv[4] = {bv4.x, bv4.y, bv4.z, bv4.w};
        for (int i = 0; i < 4; ++i)
          for (int j = 0; j < 4; ++j) acc[i][j] = fmaf(av[i], bv[j], acc[i][j]);
      }
      __syncthreads();
    }
    float* v = ws + OFF_V;
    for (int i = 0; i < 4; ++i)
      *(float4*)(v + (size_t)(rowbase + r0 + i) * 64 + m0) =
          make_float4(acc[i][0], acc[i][1], acc[i][2], acc[i][3]);
  }
}

// ---------------------------------------------------------------------------
// K_B: u[row][n] = dt * sum_m v[row][m] * MT[m][n]   (64-row tile per wg)
// ---------------------------------------------------------------------------
__global__ __launch_bounds__(256) void k_umm(float* __restrict__ ws) {
  __shared__ __align__(16) float vT[64 * 68];    // vT[m][rr]
  __shared__ __align__(16) float mts[64 * 68];   // mts[m][n]
  const int t = threadIdx.x;
  const int rowbase = blockIdx.x * 64;
  const float* v = ws + OFF_V;
  for (int i = 0; i < 4; ++i) {
    int e = 4 * (t + 256 * i);
    int rr = e >> 6, mm = e & 63;
    *(float4*)(mts + rr * 68 + mm) = *(const float4*)(ws + OFF_MT + e);
    float4 vv = *(const float4*)(v + (size_t)(rowbase + rr) * 64 + mm);
    vT[(mm + 0) * 68 + rr] = vv.x;
    vT[(mm + 1) * 68 + rr] = vv.y;
    vT[(mm + 2) * 68 + rr] = vv.z;
    vT[(mm + 3) * 68 + rr] = vv.w;
  }
  __syncthreads();
  const int r0 = 4 * (t >> 4), n0 = 4 * (t & 15);
  float acc[4][4] = {};
  for (int k = 0; k < 64; ++k) {
    float4 av4 = *(const float4*)(vT + k * 68 + r0);
    float4 bv4 = *(const float4*)(mts + k * 68 + n0);
    float av[4] = {av4.x, av4.y, av4.z, av4.w};
    float bv[4] = {bv4.x, bv4.y, bv4.z, bv4.w};
    for (int i = 0; i < 4; ++i)
      for (int j = 0; j < 4; ++j) acc[i][j] = fmaf(av[i], bv[j], acc[i][j]);
  }
  float* u = ws + OFF_U;
  for (int i = 0; i < 4; ++i)
    *(float4*)(u + (size_t)(rowbase + r0 + i) * 64 + n0) =
        make_float4(0.1f * acc[i][0], 0.1f * acc[i][1], 0.1f * acc[i][2],
                    0.1f * acc[i][3]);
}

// ---------------------------------------------------------------------------
// Scan helpers: 64x64 matvec step. areg[j] = M[r][16q+j]; h in LDS.
// ---------------------------------------------------------------------------
__device__ __forceinline__ void load_areg(const float* __restrict__ M, int r,
                                          int q, float areg[16]) {
  const float4* ap = (const float4*)(M + r * 64 + q * 16);
  float4 a0 = ap[0], a1 = ap[1], a2 = ap[2], a3 = ap[3];
  areg[0] = a0.x; areg[1] = a0.y; areg[2] = a0.z; areg[3] = a0.w;
  areg[4] = a1.x; areg[5] = a1.y; areg[6] = a1.z; areg[7] = a1.w;
  areg[8] = a2.x; areg[9] = a2.y; areg[10] = a2.z; areg[11] = a2.w;
  areg[12] = a3.x; areg[13] = a3.y; areg[14] = a3.z; areg[15] = a3.w;
}

// computes partial products, barrier, returns reduced matvec row (valid t<64)
__device__ __forceinline__ float matvec_step(const float areg[16],
                                             const float* __restrict__ hcur,
                                             float* __restrict__ part, int r,
                                             int q, int t) {
  float4 ha = *(const float4*)(hcur + q * 16);
  float4 hb = *(const float4*)(hcur + q * 16 + 4);
  float4 hc = *(const float4*)(hcur + q * 16 + 8);
  float4 hd = *(const float4*)(hcur + q * 16 + 12);
  float p0 = fmaf(areg[0], ha.x, fmaf(areg[4], hb.x, fmaf(areg[8], hc.x, areg[12] * hd.x)));
  float p1 = fmaf(areg[1], ha.y, fmaf(areg[5], hb.y, fmaf(areg[9], hc.y, areg[13] * hd.y)));
  float p2 = fmaf(areg[2], ha.z, fmaf(areg[6], hb.z, fmaf(areg[10], hc.z, areg[14] * hd.z)));
  float p3 = fmaf(areg[3], ha.w, fmaf(areg[7], hb.w, fmaf(areg[11], hc.w, areg[15] * hd.w)));
  part[q * 68 + r] = (p0 + p1) + (p2 + p3);
  __syncthreads();
  float s = 0.0f;
  if (t < 64) s = part[t] + part[68 + t] + part[136 + t] + part[204 + t];
  return s;
}

// ---------------------------------------------------------------------------
// K4/K6: chunk-local scan. phase=1: h0=0, emit final state to S.
//        phase=3: h0=INST[b][c], emit every h to H.
// ---------------------------------------------------------------------------
__global__ __launch_bounds__(256) void k_chunk(float* __restrict__ ws, int phase) {
  __shared__ __align__(16) float hcur[64];
  __shared__ __align__(16) float part[4 * 68];
  __shared__ __align__(16) float ulds[CHUNK * 64];
  const int t = threadIdx.x;
  const int c = blockIdx.x, b = blockIdx.y;
  const int r = t & 63, q = t >> 6;
  float areg[16];
  load_areg(ws + OFF_AT, r, q, areg);
  const float* u = ws + OFF_U + (size_t)(b * LEN + c * CHUNK) * 64;
  for (int i = 0; i < 4; ++i) {
    int e = 4 * (t + 256 * i);
    *(float4*)(ulds + e) = *(const float4*)(u + e);
  }
  if (t < 64)
    hcur[t] = (phase == 3) ? ws[OFF_INST + (b * NCHUNK + c) * 64 + t] : 0.0f;
  __syncthreads();
  for (int st = 0; st < CHUNK; ++st) {
    float s = matvec_step(areg, hcur, part, r, q, t);
    if (t < 64) {
      float hn = s + ulds[st * 64 + t];
      hcur[t] = hn;
      if (phase == 3)
        ws[OFF_H + (size_t)(b * LEN + c * CHUNK + st) * 64 + t] = hn;
      else if (st == CHUNK - 1)
        ws[OFF_S + (b * NCHUNK + c) * 64 + t] = hn;
    }
    __syncthreads();
  }
}

// ---------------------------------------------------------------------------
// K5: sequential carry combine per batch: INST[b][0]=0,
//     INST[b][c] = A64 @ INST[b][c-1] + S[b][c-1]
// ---------------------------------------------------------------------------
__global__ __launch_bounds__(256) void k_carry(float* __restrict__ ws) {
  __shared__ __align__(16) float hcur[64];
  __shared__ __align__(16) float part[4 * 68];
  __shared__ __align__(16) float slds[NCHUNK * 64];
  const int t = threadIdx.x;
  const int b = blockIdx.x;
  const int r = t & 63, q = t >> 6;
  float areg[16];
  load_areg(ws + OFF_A64, r, q, areg);
  for (int i = 0; i < 2; ++i) {
    int e = 4 * (t + 256 * i);                 // 0..2044
    *(float4*)(slds + e) = *(const float4*)(ws + OFF_S + b * NCHUNK * 64 + e);
  }
  if (t < 64) {
    hcur[t] = 0.0f;
    ws[OFF_INST + (b * NCHUNK) * 64 + t] = 0.0f;
  }
  __syncthreads();
  for (int c = 1; c < NCHUNK; ++c) {
    float s = matvec_step(areg, hcur, part, r, q, t);
    if (t < 64) {
      float hn = s + slds[(c - 1) * 64 + t];
      hcur[t] = hn;
      ws[OFF_INST + (b * NCHUNK + c) * 64 + t] = hn;
    }
    __syncthreads();
  }
}

// ---------------------------------------------------------------------------
// K7: y[row][o] = sum_n h[row][n] * C[o][n]  (64-row x 64-o tile per wg)
// ---------------------------------------------------------------------------
__global__ __launch_bounds__(256) void k_ygemm(const float* __restrict__ Cm,
                                               const float* __restrict__ ws,
                                               float* __restrict__ y) {
  __shared__ __align__(16) float hs[64 * 68];
  __shared__ __align__(16) float cs[64 * 68];
  const int t = threadIdx.x;
  const int rowbase = blockIdx.x * 64;
  const int o0 = blockIdx.y * 64;
  const float* h = ws + OFF_H;
  for (int i = 0; i < 4; ++i) {
    int e = 4 * (t + 256 * i);
    int rr = e >> 6, nn = e & 63;
    *(float4*)(hs + rr * 68 + nn) =
        *(const float4*)(h + (size_t)rowbase * 64 + e);
    float4 cv = *(const float4*)(Cm + (size_t)(o0 + rr) * 64 + nn);
    cs[(nn + 0) * 68 + rr] = cv.x;     // transposed: cs[n][o']
    cs[(nn + 1) * 68 + rr] = cv.y;
    cs[(nn + 2) * 68 + rr] = cv.z;
    cs[(nn + 3) * 68 + rr] = cv.w;
  }
  __syncthreads();
  const int tr = t >> 4, tc = t & 15;
  const int r0 = tr * 4, c0 = tc * 4;
  float acc[4][4] = {};
  for (int k = 0; k < 64; ++k) {
    float4 cv4 = *(const float4*)(cs + k * 68 + c0);
    float cv[4] = {cv4.x, cv4.y, cv4.z, cv4.w};
    for (int i = 0; i < 4; ++i) {
      float hv = hs[(r0 + i) * 68 + k];
      for (int j = 0; j < 4; ++j) acc[i][j] = fmaf(hv, cv[j], acc[i][j]);
    }
  }
  for (int i = 0; i < 4; ++i)
    *(float4*)(y + (size_t)(rowbase + r0 + i) * 256 + o0 + c0) =
        make_float4(acc[i][0], acc[i][1], acc[i][2], acc[i][3]);
}

// ---------------------------------------------------------------------------
extern "C" void kernel_launch(void* const* d_in, const int* in_sizes, int n_in,
                              void* d_out, int out_size, void* d_ws,
                              size_t ws_size, hipStream_t stream) {
  const float* x = (const float*)d_in[0];
  const float* A = (const float*)d_in[1];
  const float* Bm = (const float*)d_in[2];
  const float* Cm = (const float*)d_in[3];
  float* y = (float*)d_out;
  float* ws = (float*)d_ws;
  if (ws_size < (size_t)WS_FLOATS * sizeof(float)) return;  // scratch too small

  hipLaunchKernelGGL(k_fused0, dim3(1 + ROWS / 64), dim3(256), 0, stream, A, Bm,
                     x, ws);
  hipLaunchKernelGGL(k_umm, dim3(ROWS / 64), dim3(256), 0, stream, ws);
  hipLaunchKernelGGL(k_chunk, dim3(NCHUNK, B_SZ), dim3(256), 0, stream, ws, 1);
  hipLaunchKernelGGL(k_carry, dim3(B_SZ), dim3(256), 0, stream, ws);
  hipLaunchKernelGGL(k_chunk, dim3(NCHUNK, B_SZ), dim3(256), 0, stream, ws, 3);
  hipLaunchKernelGGL(k_ygemm, dim3(ROWS / 64, OUTD / 64), dim3(256), 0, stream,
                     Cm, ws, y);
}